// Round 9
// baseline (247.990 us; speedup 1.0000x reference)
//
#include <hip/hip_runtime.h>
#include <math.h>

#define NK 256
#define NT 128
#define NC 32
#define ND 10
#define NSPK 1000000
#define LOG2PI 1.8378770664093453f
#define LOG2E 1.4426950408889634f
#define LN2 0.6931471805599453f
#define SGRID ((NSPK + 255) / 256)     // 3907 one-shot blocks
#define WSTR 68                        // floats per comp row (66 + pad), 272 B

typedef __attribute__((ext_vector_type(2))) float floatx2;

// ws layout:
//   [0,8)       double acc
//   [8,12)      uint done-counter
//   [64,320)    float cpack[64] : [c] = cst_c (unscaled)
//   [1024,..)   float wq[NC][WSTR] : fp32 coefs * LOG2E, 33 float2 pairs + pad
//   [16384,..)  float pisT[NK*NT][32] : (log_pi + cst) * LOG2E, 128 B rows

// ============================ PREP 1: coefs + scalars ======================
__global__ void prep1_kernel(const float* __restrict__ means,
                             const float* __restrict__ covs,
                             const float* __restrict__ b_mu,
                             const float* __restrict__ b_ls,
                             const float* __restrict__ beta_mu,
                             const float* __restrict__ beta_ls,
                             float* __restrict__ wq,
                             float* __restrict__ cpack,
                             double* __restrict__ acc,
                             unsigned int* __restrict__ counter) {
  int blk = blockIdx.x;
  int tid = threadIdx.x;

  if (blk == 0) {
    int c = tid;
    if (c >= NC) return;

    float M[ND][ND];
    #pragma unroll
    for (int i = 0; i < ND; ++i)
      #pragma unroll
      for (int j = 0; j < ND; ++j)
        M[i][j] = covs[c * ND * ND + i * ND + j];

    // Cholesky, lower triangle in place
    float logdet = 0.f;
    #pragma unroll
    for (int j = 0; j < ND; ++j) {
      float d = M[j][j];
      #pragma unroll
      for (int k = 0; k < ND; ++k) if (k < j) d -= M[j][k] * M[j][k];
      float sq = sqrtf(d);
      M[j][j] = sq;
      logdet += 2.f * __logf(sq);
      float inv = 1.f / sq;
      #pragma unroll
      for (int i = 0; i < ND; ++i) {
        if (i > j) {
          float s2 = M[i][j];
          #pragma unroll
          for (int k = 0; k < ND; ++k) if (k < j) s2 -= M[i][k] * M[j][k];
          M[i][j] = s2 * inv;
        }
      }
    }

    // invert lower triangle in place: M(lower) := L^-1
    #pragma unroll
    for (int j = 0; j < ND; ++j) {
      M[j][j] = 1.f / M[j][j];
      #pragma unroll
      for (int i = 0; i < ND; ++i) {
        if (i > j) {
          float s2 = 0.f;
          #pragma unroll
          for (int k = 0; k < ND; ++k) if (k >= j && k < i) s2 += M[i][k] * M[k][j];
          M[i][j] = -s2 / M[i][i];
        }
      }
    }

    // P = Li^T Li : off-diag -> upper triangle of M, diag -> pd[]
    float pd[ND];
    #pragma unroll
    for (int i = 0; i < ND; ++i) {
      #pragma unroll
      for (int jj = 0; jj < ND; ++jj) {
        if (jj >= i) {
          float s2 = 0.f;
          #pragma unroll
          for (int k = 0; k < ND; ++k) if (k >= jj) s2 += M[k][i] * M[k][jj];
          if (jj > i) M[i][jj] = s2;
          else pd[i] = s2;
        }
      }
    }

    float mu[ND], qv[ND];
    #pragma unroll
    for (int i = 0; i < ND; ++i) mu[i] = means[c * ND + i];
    float muPmu = 0.f;
    #pragma unroll
    for (int i = 0; i < ND; ++i) {
      float a2 = pd[i] * mu[i];
      #pragma unroll
      for (int j = 0; j < ND; ++j) {
        if (j < i) a2 += M[j][i] * mu[j];
        if (j > i) a2 += M[i][j] * mu[j];
      }
      qv[i] = a2;
      muPmu += mu[i] * a2;
    }
    float cst = -0.5f * ((float)ND * LOG2PI + logdet + muPmu);

    // 66-coef vector: all 55 pairs (incl (9,9)) + 10 linear + zero const slot
    float wv[WSTR];
    int p = 0;
    #pragma unroll
    for (int i = 0; i < ND; ++i)
      #pragma unroll
      for (int j = i; j < ND; ++j)
        wv[p++] = (i == j) ? -0.5f * pd[i] : -M[i][j];
    #pragma unroll
    for (int i = 0; i < ND; ++i) wv[55 + i] = qv[i];
    wv[65] = 0.f; wv[66] = 0.f; wv[67] = 0.f;

    #pragma unroll
    for (int k = 0; k < WSTR; ++k) wq[c * WSTR + k] = wv[k] * LOG2E;
    cpack[c] = cst;

  } else {
    // prior - q scalar terms -> plain-store acc, init counter
    float local = 0.f;
    for (int i = tid; i < NC; i += 256)
      local += fmaf(-0.5f * b_mu[i], b_mu[i], b_ls[i]);
    for (int i = tid; i < NC * NT; i += 256)
      local += fmaf(-0.5f * beta_mu[i], beta_mu[i], beta_ls[i]);
    #pragma unroll
    for (int off = 32; off > 0; off >>= 1) local += __shfl_down(local, off);
    __shared__ float red[4];
    if ((tid & 63) == 0) red[tid >> 6] = local;
    __syncthreads();
    if (tid == 0) {
      acc[0] = (double)(red[0] + red[1] + red[2] + red[3]);
      counter[0] = 0u;
    }
  }
}

// ====== PREP 2: log-softmax table, cst folded, pre-scaled by LOG2E =========
__global__ void prep2_kernel(const float* __restrict__ y,
                             const float* __restrict__ b_mu,
                             const float* __restrict__ beta_mu,
                             const float* __restrict__ cpack,
                             float* __restrict__ pisT) {
  int id = blockIdx.x * 256 + threadIdx.x;   // id = k*NT + t
  int t = id & (NT - 1);
  float yv = y[id];
  float v[NC];
  float m = -1e30f;
  #pragma unroll
  for (int c = 0; c < NC; ++c) {
    v[c] = fmaf(beta_mu[c * NT + t], yv, b_mu[c]);
    m = fmaxf(m, v[c]);
  }
  float ssum = 0.f;
  #pragma unroll
  for (int c = 0; c < NC; ++c) ssum += __expf(v[c] - m);
  float lz = m + __logf(ssum);
  float* outp = pisT + (size_t)id * NC;
  #pragma unroll
  for (int c = 0; c < NC; ++c)
    outp[c] = (v[c] - lz + cpack[c]) * LOG2E;
}

// ========== MAIN: straight-line VALU, packed-pair FMAs, no LDS =============
__global__ void __launch_bounds__(256)
__attribute__((amdgpu_waves_per_eu(4, 4)))
spike_kernel(const float* __restrict__ s,
             const int* __restrict__ ks,
             const int* __restrict__ ts,
             const float* __restrict__ wq,
             const float* __restrict__ pisT,
             double* __restrict__ acc,
             unsigned int* __restrict__ counter,
             float* __restrict__ out) {
  int tid = threadIdx.x;
  int n = blockIdx.x * 256 + tid;
  bool active = n < NSPK;
  int nc = active ? n : (NSPK - 1);

  // s row (5 x float2) and gather row index
  const float2* srow = (const float2*)(s + (size_t)nc * ND);
  float sv[ND];
  #pragma unroll
  for (int i = 0; i < 5; ++i) {
    float2 v2 = srow[i];
    sv[2 * i] = v2.x;
    sv[2 * i + 1] = v2.y;
  }
  int kt = ks[nc] * NT + ts[nc];

  // lp gather: 128 B row, 8 x float4 (consumed progressively below)
  const float4* lpp = (const float4*)(pisT + (size_t)kt * NC);
  float4 lpv[8];
  #pragma unroll
  for (int i = 0; i < 8; ++i) lpv[i] = lpp[i];

  // 66-feature vector as 33 float2 pairs: 55 products + 10 linear + 1.0
  floatx2 fv[33];
  {
    float f[66];
    int p = 0;
    #pragma unroll
    for (int i = 0; i < ND; ++i)
      #pragma unroll
      for (int j = i; j < ND; ++j) f[p++] = sv[i] * sv[j];
    #pragma unroll
    for (int i = 0; i < ND; ++i) f[55 + i] = sv[i];
    f[65] = 1.f;
    #pragma unroll
    for (int k = 0; k < 33; ++k) fv[k] = (floatx2){f[2 * k], f[2 * k + 1]};
  }

  // streamed components: acc2 = {lp_c, 0}; 33 pk-FMAs; ssum += exp2(x+y)
  // m-hat = 0 is overflow-safe: logits*log2e <= -13 always (cst <= -9.2)
  float ssum = 1e-35f;
  #pragma unroll
  for (int c = 0; c < NC; ++c) {
    const floatx2* wr = (const floatx2*)(wq + c * WSTR);   // wave-uniform
    float lpc = ((const float*)&lpv[c >> 2])[c & 3];
    floatx2 a2 = {lpc, 0.f};
    #pragma unroll
    for (int j = 0; j < 33; ++j)
      a2 = __builtin_elementwise_fma(wr[j], fv[j], a2);
    ssum += __builtin_amdgcn_exp2f(a2.x + a2.y);
  }
  float lse = active ? (LN2 * __builtin_amdgcn_logf(ssum)) : 0.f;

  // block reduction -> one fp64 atomic per block
  #pragma unroll
  for (int off = 32; off > 0; off >>= 1) lse += __shfl_down(lse, off);
  __shared__ float red[4];
  if ((tid & 63) == 0) red[tid >> 6] = lse;
  __syncthreads();
  if (tid == 0) {
    atomicAdd(acc, (double)(red[0] + red[1] + red[2] + red[3]));
    __threadfence();
    unsigned int old = atomicAdd(counter, 1u);
    if (old == SGRID - 1) {
      __threadfence();
      double v = atomicAdd(acc, 0.0);
      out[0] = (float)v;
    }
  }
}

extern "C" void kernel_launch(void* const* d_in, const int* in_sizes, int n_in,
                              void* d_out, int out_size, void* d_ws, size_t ws_size,
                              hipStream_t stream) {
  const float* s       = (const float*)d_in[0];
  const float* y       = (const float*)d_in[1];
  const int*   ks      = (const int*)d_in[2];
  const int*   ts      = (const int*)d_in[3];
  const float* means   = (const float*)d_in[4];
  const float* covs    = (const float*)d_in[5];
  const float* b_mu    = (const float*)d_in[6];
  const float* b_ls    = (const float*)d_in[7];
  const float* beta_mu = (const float*)d_in[8];
  const float* beta_ls = (const float*)d_in[9];
  float* out = (float*)d_out;

  char* ws = (char*)d_ws;
  double* acc           = (double*)ws;
  unsigned int* counter = (unsigned int*)(ws + 8);
  float* cpack          = (float*)(ws + 64);
  float* wq             = (float*)(ws + 1024);
  float* pisT           = (float*)(ws + 16384);

  prep1_kernel<<<2, 256, 0, stream>>>(
      means, covs, b_mu, b_ls, beta_mu, beta_ls, wq, cpack, acc, counter);
  prep2_kernel<<<(NK * NT) / 256, 256, 0, stream>>>(
      y, b_mu, beta_mu, cpack, pisT);
  spike_kernel<<<SGRID, 256, 0, stream>>>(
      s, ks, ts, wq, pisT, acc, counter, out);
}